// Round 7
// baseline (203.367 us; speedup 1.0000x reference)
//
#include <hip/hip_runtime.h>
#include <hip/hip_bf16.h>
#include <stdint.h>

#define B_  2
#define S_  2048
#define D_  1024
#define H_  16
#define DH_ 64

typedef __attribute__((ext_vector_type(8))) __bf16    bf16x8;
typedef __attribute__((ext_vector_type(8))) _Float16  f16x8;
typedef __attribute__((ext_vector_type(4))) _Float16  f16x4;
typedef __attribute__((ext_vector_type(2))) __fp16    fp16x2;   // cvt_pkrtz return type
typedef __attribute__((ext_vector_type(4))) float     f32x4;

__device__ inline unsigned short f2bf(float f) {
    union { float f; uint32_t u; } v; v.f = f;
    uint32_t r = (v.u + 0x7fffu + ((v.u >> 16) & 1u)) >> 16;
    return (unsigned short)r;
}

// async global->LDS, 16B per lane. LDS dest = wave-uniform base + lane*16.
__device__ __forceinline__ void g2l16(const unsigned short* g, unsigned short* l) {
    __builtin_amdgcn_global_load_lds(
        (const __attribute__((address_space(1))) unsigned int*)g,
        (__attribute__((address_space(3))) unsigned int*)l,
        16, 0, 0);
}

// ---------------- conversion kernels ----------------

__global__ void convert_x(const float* __restrict__ x, unsigned short* __restrict__ xb, int n) {
    int i = (blockIdx.x * blockDim.x + threadIdx.x) * 4;
    if (i < n) {
        float4 v = *(const float4*)(x + i);
        ushort4 o;
        o.x = f2bf(v.x); o.y = f2bf(v.y); o.z = f2bf(v.z); o.w = f2bf(v.w);
        *(ushort4*)(xb + i) = o;
    }
}

// transpose+convert 1024x1024 fp32 [K][N] -> bf16 [N][K]; z selects matrix
__global__ void transpose_w(const float* __restrict__ s0, const float* __restrict__ s1,
                            const float* __restrict__ s2, const float* __restrict__ s3,
                            unsigned short* __restrict__ d0, unsigned short* __restrict__ d1,
                            unsigned short* __restrict__ d2, unsigned short* __restrict__ d3) {
    __shared__ float tile[32][33];
    const float* src; unsigned short* dst;
    switch (blockIdx.z) {
        case 0: src = s0; dst = d0; break;
        case 1: src = s1; dst = d1; break;
        case 2: src = s2; dst = d2; break;
        default: src = s3; dst = d3; break;
    }
    int n0 = blockIdx.x * 32, k0 = blockIdx.y * 32;
    int tx = threadIdx.x, ty = threadIdx.y;   // (32, 8)
    for (int j = 0; j < 32; j += 8)
        tile[ty + j][tx] = src[(long)(k0 + ty + j) * 1024 + n0 + tx];
    __syncthreads();
    for (int j = 0; j < 32; j += 8)
        dst[(long)(n0 + ty + j) * 1024 + k0 + tx] = f2bf(tile[tx][ty + j]);
}

// ---------------- 128x128 MFMA GEMM (gemm0), double-buffered staging ----------------
// R16: R6 counters showed MfmaUtil 18.9 + VALUBusy 12.3 = 31% busy, 69% idle:
// the single-buffered loop (barrier; stage; barrier-with-vmcnt0-drain; compute)
// serially exposes ~900cy of staging latency per 16 K-iters. Fix = attn's
// proven dbuf pattern: issue stage(t+1) into buf^1 BEFORE compute(t); the
// end-of-iter barrier's vmcnt(0) drain then lands after a full compute phase.
// One barrier/iter. LDS 64KB/block -> still 2 blocks/CU.
// Scatter epilogue -> Q[B,H,S,64] bf16 (PRE-SCALED by 0.125*log2e),
// K[B,H,S,64] bf16 (PRE-SCALED by fw[s]), Vt[B,H,64,S] FP16 with per-row
// half-swap s ^ ((d&8)?4:0) (R13 source side of attn V bank fix).
__global__ __launch_bounds__(256, 2)
void gemm128(const unsigned short* __restrict__ A, const unsigned short* __restrict__ Bt,
             unsigned short* __restrict__ Qo, unsigned short* __restrict__ Ko,
             unsigned short* __restrict__ Vt,
             const float* __restrict__ fw)
{
    __shared__ __align__(16) unsigned short As[2][128 * 64];
    __shared__ __align__(16) unsigned short Bs[2][128 * 64];
    const int tid  = threadIdx.x;
    const int lane = tid & 63, wid = tid >> 6;
    const int quad = lane >> 4, l15 = lane & 15;
    const int wm = wid >> 1, wn = wid & 1;
    const int bm = blockIdx.y, bn = blockIdx.x;
    const int K = 1024;
    f32x4 acc[4][4] = {};
    const long Abase = (long)bm * 128 * K;
    const long Bbase = (long)bn * 128 * K;

    auto stage = [&](int buf, int k0) {
#pragma unroll
        for (int i = 0; i < 4; i++) {
            int slot = i * 256 + wid * 64 + lane;
            int row = slot >> 3, cp = slot & 7;
            int c = cp ^ (row & 7);
            g2l16(A + Abase + (long)row * K + k0 + c * 8, &As[buf][(i * 256 + wid * 64) * 8]);
        }
#pragma unroll
        for (int i = 0; i < 4; i++) {
            int slot = i * 256 + wid * 64 + lane;
            int row = slot >> 3, cp = slot & 7;
            int c = cp ^ (row & 7);
            g2l16(Bt + Bbase + (long)row * K + k0 + c * 8, &Bs[buf][(i * 256 + wid * 64) * 8]);
        }
    };

    stage(0, 0);
    __syncthreads();

    for (int t = 0; t < 16; t++) {
        const int cur = t & 1;
        if (t + 1 < 16) stage(1 - cur, (t + 1) * 64);
#pragma unroll
        for (int ks = 0; ks < 2; ks++) {
            bf16x8 af[4], bfr[4];
#pragma unroll
            for (int tt = 0; tt < 4; tt++) {
                int ra = wm * 64 + tt * 16 + l15;
                af[tt]  = *(const bf16x8*)(&As[cur][0] + ra * 64 + (((ks * 4 + quad) ^ (l15 & 7))) * 8);
                int rb = wn * 64 + tt * 16 + l15;
                bfr[tt] = *(const bf16x8*)(&Bs[cur][0] + rb * 64 + (((ks * 4 + quad) ^ (l15 & 7))) * 8);
            }
#pragma unroll
            for (int tm = 0; tm < 4; tm++)
#pragma unroll
                for (int tn = 0; tn < 4; tn++)
                    acc[tm][tn] = __builtin_amdgcn_mfma_f32_16x16x32_bf16(af[tm], bfr[tn], acc[tm][tn], 0, 0, 0);
        }
        __syncthreads();
    }

    const float Cq = 0.125f * 1.44269504f;   // score scale * log2(e), folded into Q
    for (int tm = 0; tm < 4; tm++)
        for (int tn = 0; tn < 4; tn++)
            for (int r = 0; r < 4; r++) {
                int gm = bm * 128 + wm * 64 + tm * 16 + quad * 4 + r;
                int gn = bn * 128 + wn * 64 + tn * 16 + l15;
                float v = acc[tm][tn][r];
                int b = gm >> 11, s = gm & 2047;
                if (gn < 1024) {
                    int h = gn >> 6, d = gn & 63;
                    Qo[(((long)(b * H_ + h) * S_ + s) << 6) + d] = f2bf(v * Cq);
                } else if (gn < 2048) {
                    int g = gn - 1024; int h = g >> 6, d = g & 63;
                    Ko[(((long)(b * H_ + h) * S_ + s) << 6) + d] = f2bf(v * fw[s]);
                } else {
                    int g = gn - 2048; int h = g >> 6, d = g & 63;
                    union { _Float16 h; unsigned short u; } cv;
                    cv.h = (_Float16)v;                       // V^T stored FP16
                    int sp = s ^ ((d & 8) ? 4 : 0);           // R13 half-swap involution
                    Vt[((long)(b * H_ + h) * DH_ + d) * S_ + sp] = cv.u;
                }
            }
}

// ---------------- 128x64 MFMA GEMM (gemm1 / Wo projection), double-buffered ----------------
// R15: BN=64 -> 512 blocks = 2 blocks/CU, 8 waves/CU. R16: same dbuf pattern
// as gemm128 (48KB LDS).
__global__ __launch_bounds__(256, 2)
void gemm_wo(const unsigned short* __restrict__ A, const unsigned short* __restrict__ Bt,
             float* __restrict__ Cout)
{
    __shared__ __align__(16) unsigned short As[2][128 * 64];
    __shared__ __align__(16) unsigned short Bs[2][64 * 64];
    const int tid  = threadIdx.x;
    const int lane = tid & 63, wid = tid >> 6;
    const int quad = lane >> 4, l15 = lane & 15;
    const int bm = blockIdx.y, bn = blockIdx.x;
    const int K = 1024;
    f32x4 acc[2][4] = {};
    const long Abase = (long)bm * 128 * K;
    const long Bbase = (long)bn * 64 * K;

    auto stage = [&](int buf, int k0) {
#pragma unroll
        for (int i = 0; i < 4; i++) {
            int slot = i * 256 + wid * 64 + lane;
            int row = slot >> 3, cp = slot & 7;
            int c = cp ^ (row & 7);
            g2l16(A + Abase + (long)row * K + k0 + c * 8, &As[buf][(i * 256 + wid * 64) * 8]);
        }
#pragma unroll
        for (int i = 0; i < 2; i++) {
            int slot = i * 256 + wid * 64 + lane;
            int row = slot >> 3, cp = slot & 7;
            int c = cp ^ (row & 7);
            g2l16(Bt + Bbase + (long)row * K + k0 + c * 8, &Bs[buf][(i * 256 + wid * 64) * 8]);
        }
    };

    stage(0, 0);
    __syncthreads();

    for (int t = 0; t < 16; t++) {
        const int cur = t & 1;
        if (t + 1 < 16) stage(1 - cur, (t + 1) * 64);
#pragma unroll
        for (int ks = 0; ks < 2; ks++) {
            bf16x8 af[2], bfr[4];
#pragma unroll
            for (int tt = 0; tt < 2; tt++) {
                int ra = wid * 32 + tt * 16 + l15;
                af[tt]  = *(const bf16x8*)(&As[cur][0] + ra * 64 + (((ks * 4 + quad) ^ (l15 & 7))) * 8);
            }
#pragma unroll
            for (int tt = 0; tt < 4; tt++) {
                int rb = tt * 16 + l15;
                bfr[tt] = *(const bf16x8*)(&Bs[cur][0] + rb * 64 + (((ks * 4 + quad) ^ (l15 & 7))) * 8);
            }
#pragma unroll
            for (int tm = 0; tm < 2; tm++)
#pragma unroll
                for (int tn = 0; tn < 4; tn++)
                    acc[tm][tn] = __builtin_amdgcn_mfma_f32_16x16x32_bf16(af[tm], bfr[tn], acc[tm][tn], 0, 0, 0);
        }
        __syncthreads();
    }

    for (int tm = 0; tm < 2; tm++)
        for (int tn = 0; tn < 4; tn++)
            for (int r = 0; r < 4; r++) {
                int gm = bm * 128 + wid * 32 + tm * 16 + quad * 4 + r;
                int gn = bn * 64 + tn * 16 + l15;
                Cout[(long)gm * 1024 + gn] = acc[tm][tn][r];
            }
}

// ---------------- flash attention: in-block split-K ----------------
// R14: split-K. Softmax is MAX-FREE (pure exp2, fw sums to 1) => partial
// (O, l) over key halves are DIRECTLY ADDABLE - no rescale. Block = 512 thr
// = 8 waves: waves 0-3 do keys [0,1024), waves 4-7 keys [1024,2048), each
// wave at 32 q-rows (2 strips SHARING K/V fragments). 16 waves/CU.
// Combine: upper half writes fp32 partial O (+l) into the dead K/V LDS,
// one barrier, lower half adds+normalizes+stores.
// R15: V-fragment preload before exp2 (LDS drains under VALU).
// l via MFMA (R14b). Register-P (R8), PV K=32 f16 key-permutation packing
// (R10), V half-swap bank fix (R13b, conflicts 4.19M -> 0) retained.
__global__ __launch_bounds__(512, 4)
void attn_kernel(const unsigned short* __restrict__ Q, const unsigned short* __restrict__ Kb,
                 const unsigned short* __restrict__ Vt,
                 unsigned short* __restrict__ O)
{
    // [half][buf][K=0/V=1][64*64 shorts] = 64 KB
    __shared__ __align__(16) unsigned short smem[2][2][2][64 * 64];

    const int tid  = threadIdx.x;
    const int lane = tid & 63, wid = tid >> 6;    // wid in {0..7}
    const int half = wid >> 2, sw = wid & 3;      // key-half, sub-wave
    const int quad = lane >> 4, l15 = lane & 15;
    const int bh = blockIdx.y;
    const int qt = blockIdx.x;                    // 128 q-rows per block, 32 per wave

    const unsigned short* Kg = Kb + (long)bh * S_ * DH_;
    const unsigned short* Vg = Vt + (long)bh * (long)DH_ * S_;

    bf16x8 qf[2][2];
#pragma unroll
    for (int st = 0; st < 2; st++) {
        const unsigned short* Qp = Q + ((long)bh * S_ + qt * 128 + sw * 32 + st * 16 + l15) * DH_ + quad * 8;
        qf[st][0] = *(const bf16x8*)(Qp);
        qf[st][1] = *(const bf16x8*)(Qp + 32);
    }

    // stage absolute tile kt into this half's buffer: 512 chunks K + 512 V,
    // 4 sub-waves x 2 rounds each
    auto issue = [&](int buf, int kt) {
#pragma unroll
        for (int i = 0; i < 2; i++) {
            int base = i * 256 + sw * 64;
            int slot = base + lane;
            int row = slot >> 3, cp = slot & 7;
            int c = cp ^ (row & 7);
            g2l16(Kg + ((long)(kt * 64 + row) * 64 + c * 8), &smem[half][buf][0][base * 8]);
        }
#pragma unroll
        for (int i = 0; i < 2; i++) {
            int base = i * 256 + sw * 64;
            int slot = base + lane;
            int row = slot >> 3, cp = slot & 7;
            int c = cp ^ (row & 7);
            g2l16(Vg + ((long)row * S_ + kt * 64 + c * 8), &smem[half][buf][1][base * 8]);
        }
    };

    f32x4 oacc[2][4] = {};
    f32x4 lacc[2] = {};
    const f16x8 vone = {(_Float16)1.f, (_Float16)1.f, (_Float16)1.f, (_Float16)1.f,
                        (_Float16)1.f, (_Float16)1.f, (_Float16)1.f, (_Float16)1.f};

    const int kt0 = half * 16;                    // 16 tiles per half
    issue(0, kt0);
    __syncthreads();

    const int hf = (((quad & 1) ^ ((l15 >> 3) & 1))) * 4;   // R13b bank fix

    for (int t = 0; t < 16; t++) {
        const int cur = t & 1;
        if (t + 1 < 16) issue(1 - cur, kt0 + t + 1);

        const unsigned short* Kc = &smem[half][cur][0][0];
        const unsigned short* Vc = &smem[half][cur][1][0];

        // ---- S^T tiles: mfma(K_frag, Q_frag) -> [key=quad*4+r][q=l15] ----
        f32x4 sacc[2][4] = {};
#pragma unroll
        for (int kc = 0; kc < 4; kc++) {
            int row = kc * 16 + l15;
            bf16x8 k0 = *(const bf16x8*)(Kc + (row * 8 + (quad       ^ (l15 & 7))) * 8);
            bf16x8 k1 = *(const bf16x8*)(Kc + (row * 8 + ((4 + quad) ^ (l15 & 7))) * 8);
#pragma unroll
            for (int st = 0; st < 2; st++) {
                sacc[st][kc] = __builtin_amdgcn_mfma_f32_16x16x32_bf16(k0, qf[st][0], sacc[st][kc], 0, 0, 0);
                sacc[st][kc] = __builtin_amdgcn_mfma_f32_16x16x32_bf16(k1, qf[st][1], sacc[st][kc], 0, 0, 0);
            }
        }

        // ---- R15: preload ALL V fragments now; LDS drains under exp2 ----
        f16x8 vfr[2][4];
#pragma unroll
        for (int c = 0; c < 2; c++)
#pragma unroll
            for (int dt = 0; dt < 4; dt++) {
                int row = dt * 16 + l15;
                int p0 = (c * 4 +     (quad >> 1)) ^ (l15 & 7);
                int p1 = (c * 4 + 2 + (quad >> 1)) ^ (l15 & 7);
                f16x4 v0 = *(const f16x4*)(Vc + row * 64 + p0 * 8 + hf);
                f16x4 v1 = *(const f16x4*)(Vc + row * 64 + p1 * 8 + hf);
                vfr[c][dt] = __builtin_shufflevector(v0, v1, 0, 1, 2, 3, 4, 5, 6, 7);
            }

        // ---- p = 2^sacc packed into K=32 f16 PV A-fragments (R10 bijection) ----
        f16x8 pk8[2][2];
#pragma unroll
        for (int st = 0; st < 2; st++)
#pragma unroll
            for (int c = 0; c < 2; c++) {
                union { uint4 u; f16x8 v; } pku;
#pragma unroll
                for (int hh = 0; hh < 2; hh++) {
                    float p0 = __builtin_amdgcn_exp2f(sacc[st][2 * c + hh][0]);
                    float p1 = __builtin_amdgcn_exp2f(sacc[st][2 * c + hh][1]);
                    float p2 = __builtin_amdgcn_exp2f(sacc[st][2 * c + hh][2]);
                    float p3 = __builtin_amdgcn_exp2f(sacc[st][2 * c + hh][3]);
                    union { fp16x2 h2; unsigned int u; } a, b;
                    a.h2 = __builtin_amdgcn_cvt_pkrtz(p0, p1);
                    b.h2 = __builtin_amdgcn_cvt_pkrtz(p2, p3);
                    if (hh == 0) { pku.u.x = a.u; pku.u.y = b.u; }
                    else         { pku.u.z = a.u; pku.u.w = b.u; }
                }
                pk8[st][c] = pku.v;
            }

        // ---- O += P V (K=32 f16) all-register; l += P . 1 via MFMA ----
#pragma unroll
        for (int c = 0; c < 2; c++) {
            lacc[0] = __builtin_amdgcn_mfma_f32_16x16x32_f16(pk8[0][c], vone, lacc[0], 0, 0, 0);
            lacc[1] = __builtin_amdgcn_mfma_f32_16x16x32_f16(pk8[1][c], vone, lacc[1], 0, 0, 0);
#pragma unroll
            for (int dt = 0; dt < 4; dt++) {
                oacc[0][dt] = __builtin_amdgcn_mfma_f32_16x16x32_f16(pk8[0][c], vfr[c][dt], oacc[0][dt], 0, 0, 0);
                oacc[1][dt] = __builtin_amdgcn_mfma_f32_16x16x32_f16(pk8[1][c], vfr[c][dt], oacc[1][dt], 0, 0, 0);
            }
        }

        __syncthreads();
    }
    // loop ends with a full barrier: all LDS K/V reads complete -> overlay safe

    // combine overlay over the dead K/V LDS: 128 x stride-66 fp32 O + 128 fp32 l
    float* ov = (float*)&smem[0][0][0][0];
    float* lv = ov + 128 * 66;

    if (half == 1) {
#pragma unroll
        for (int st = 0; st < 2; st++) {
#pragma unroll
            for (int dt = 0; dt < 4; dt++)
#pragma unroll
                for (int r = 0; r < 4; r++) {
                    int qr = sw * 32 + st * 16 + quad * 4 + r;
                    ov[qr * 66 + dt * 16 + l15] = oacc[st][dt][r];
                }
            if (l15 == 0) {
#pragma unroll
                for (int r = 0; r < 4; r++)
                    lv[sw * 32 + st * 16 + quad * 4 + r] = lacc[st][r];
            }
        }
    }
    __syncthreads();

    if (half == 0) {
        int b = bh >> 4, h = bh & 15;
#pragma unroll
        for (int st = 0; st < 2; st++)
#pragma unroll
            for (int r = 0; r < 4; r++) {
                int qr = sw * 32 + st * 16 + quad * 4 + r;
                float inv = 1.0f / (lacc[st][r] + lv[qr]);
                int srow = qt * 128 + qr;
#pragma unroll
                for (int dt = 0; dt < 4; dt++) {
                    float val = oacc[st][dt][r] + ov[qr * 66 + dt * 16 + l15];
                    O[((long)(b * S_ + srow)) * 1024 + h * DH_ + dt * 16 + l15] = f2bf(val * inv);
                }
            }
    }
}

// ---------------- launch ----------------

extern "C" void kernel_launch(void* const* d_in, const int* in_sizes, int n_in,
                              void* d_out, int out_size, void* d_ws, size_t ws_size,
                              hipStream_t stream)
{
    const float* x  = (const float*)d_in[0];
    const float* Wq = (const float*)d_in[1];
    const float* Wk = (const float*)d_in[2];
    const float* Wv = (const float*)d_in[3];
    const float* Wo = (const float*)d_in[4];
    const float* fw = (const float*)d_in[5];
    float* out = (float*)d_out;

    char* ws = (char*)d_ws;
    unsigned short* xb    = (unsigned short*)(ws);               // 8 MB   [B*S, D] bf16
    unsigned short* WqkvT = (unsigned short*)(ws + 8388608);     // 6 MB   [3072,1024] bf16
    unsigned short* WoT   = (unsigned short*)(ws + 14680064);    // 2 MB   [1024,1024] bf16
    unsigned short* Qb    = (unsigned short*)(ws + 16777216);    // 8 MB   [B,H,S,64] bf16 (pre-scaled Cq)
    unsigned short* Kb    = (unsigned short*)(ws + 25165824);    // 8 MB   [B,H,S,64] bf16 (pre-scaled fw)
    unsigned short* Vt    = (unsigned short*)(ws + 33554432);    // 8 MB   [B,H,64,S] fp16 (half-swapped)
    unsigned short* Ob    = xb;                                  // alias: xb dead after gemm1

    convert_x<<<dim3((B_ * S_ * D_) / 4 / 256), dim3(256), 0, stream>>>(x, xb, B_ * S_ * D_);
    transpose_w<<<dim3(32, 32, 4), dim3(32, 8), 0, stream>>>(
        Wq, Wk, Wv, Wo,
        WqkvT, WqkvT + 1024 * 1024, WqkvT + 2 * 1024 * 1024, WoT);
    gemm128<<<dim3(24, 32), dim3(256), 0, stream>>>(xb, WqkvT, Qb, Kb, Vt, fw);
    attn_kernel<<<dim3(S_ / 128, B_ * H_), dim3(512), 0, stream>>>(Qb, Kb, Vt, Ob);
    gemm_wo<<<dim3(16, 32), dim3(256), 0, stream>>>(Ob, WoT, out);
}

// Round 8
// 196.401 us; speedup vs baseline: 1.0355x; 1.0355x over previous
//
#include <hip/hip_runtime.h>
#include <hip/hip_bf16.h>
#include <stdint.h>

#define B_  2
#define S_  2048
#define D_  1024
#define H_  16
#define DH_ 64

typedef __attribute__((ext_vector_type(8))) __bf16    bf16x8;
typedef __attribute__((ext_vector_type(8))) _Float16  f16x8;
typedef __attribute__((ext_vector_type(4))) _Float16  f16x4;
typedef __attribute__((ext_vector_type(2))) __fp16    fp16x2;   // cvt_pkrtz return type
typedef __attribute__((ext_vector_type(4))) float     f32x4;

__device__ inline unsigned short f2bf(float f) {
    union { float f; uint32_t u; } v; v.f = f;
    uint32_t r = (v.u + 0x7fffu + ((v.u >> 16) & 1u)) >> 16;
    return (unsigned short)r;
}

// async global->LDS, 16B per lane. LDS dest = wave-uniform base + lane*16.
__device__ __forceinline__ void g2l16(const unsigned short* g, unsigned short* l) {
    __builtin_amdgcn_global_load_lds(
        (const __attribute__((address_space(1))) unsigned int*)g,
        (__attribute__((address_space(3))) unsigned int*)l,
        16, 0, 0);
}

// ---------------- conversion kernels ----------------

__global__ void convert_x(const float* __restrict__ x, unsigned short* __restrict__ xb, int n) {
    int i = (blockIdx.x * blockDim.x + threadIdx.x) * 4;
    if (i < n) {
        float4 v = *(const float4*)(x + i);
        ushort4 o;
        o.x = f2bf(v.x); o.y = f2bf(v.y); o.z = f2bf(v.z); o.w = f2bf(v.w);
        *(ushort4*)(xb + i) = o;
    }
}

// transpose+convert 1024x1024 fp32 [K][N] -> bf16 [N][K]; z selects matrix
__global__ void transpose_w(const float* __restrict__ s0, const float* __restrict__ s1,
                            const float* __restrict__ s2, const float* __restrict__ s3,
                            unsigned short* __restrict__ d0, unsigned short* __restrict__ d1,
                            unsigned short* __restrict__ d2, unsigned short* __restrict__ d3) {
    __shared__ float tile[32][33];
    const float* src; unsigned short* dst;
    switch (blockIdx.z) {
        case 0: src = s0; dst = d0; break;
        case 1: src = s1; dst = d1; break;
        case 2: src = s2; dst = d2; break;
        default: src = s3; dst = d3; break;
    }
    int n0 = blockIdx.x * 32, k0 = blockIdx.y * 32;
    int tx = threadIdx.x, ty = threadIdx.y;   // (32, 8)
    for (int j = 0; j < 32; j += 8)
        tile[ty + j][tx] = src[(long)(k0 + ty + j) * 1024 + n0 + tx];
    __syncthreads();
    for (int j = 0; j < 32; j += 8)
        dst[(long)(n0 + ty + j) * 1024 + k0 + tx] = f2bf(tile[tx][ty + j]);
}

// ---------------- 128x128 MFMA GEMM (gemm0), BK=32 double-buffered ----------------
// R17: R16's BK=64 dbuf (64KB LDS) -> only 1 block/CU resident (measured:
// occupancy 30->15%, dur 52.7->60.7). EMPIRICAL LAW on this box: 64KB-LDS
// blocks are 1/CU. Fix: dbuf at BK=32 -> 32KB LDS total -> 2-3 blocks/CU
// restored AND pipelining kept. Totals identical to single-buffer (512 MFMA,
// 256 ds_read_b128, 32 barriers, same g2l16 count); stage quantum halves so
// the end-of-iter vmcnt drain (~300cy of 16KB from L2) hides under compute.
// BK=32 layout: row = 64B = 4 chunks of 16B; chunk swizzle c = cp ^ (row&3);
// ds_read bank check: 8 lanes per 16B bank-group x 8 groups = conflict-free.
// Scatter epilogue -> Q bf16 (PRE-SCALED 0.125*log2e), K bf16 (PRE-SCALED
// fw[s]), Vt[B,H,64,S] fp16 with half-swap s^((d&8)?4:0) (R13 attn bank fix).
__global__ __launch_bounds__(256, 2)
void gemm128(const unsigned short* __restrict__ A, const unsigned short* __restrict__ Bt,
             unsigned short* __restrict__ Qo, unsigned short* __restrict__ Ko,
             unsigned short* __restrict__ Vt,
             const float* __restrict__ fw)
{
    __shared__ __align__(16) unsigned short As[2][128 * 32];
    __shared__ __align__(16) unsigned short Bs[2][128 * 32];
    const int tid  = threadIdx.x;
    const int lane = tid & 63, wid = tid >> 6;
    const int quad = lane >> 4, l15 = lane & 15;
    const int wm = wid >> 1, wn = wid & 1;
    const int bm = blockIdx.y, bn = blockIdx.x;
    const int K = 1024;
    f32x4 acc[4][4] = {};
    const long Abase = (long)bm * 128 * K;
    const long Bbase = (long)bn * 128 * K;

    // stage 8KB A + 8KB B (128 rows x 32 cols): 512 chunks each, 2 rounds
    auto stage = [&](int buf, int k0) {
#pragma unroll
        for (int i = 0; i < 2; i++) {
            int base = i * 256 + wid * 64;
            int slot = base + lane;
            int row = slot >> 2, cp = slot & 3;
            int c = cp ^ (row & 3);
            g2l16(A + Abase + (long)row * K + k0 + c * 8, &As[buf][base * 8]);
        }
#pragma unroll
        for (int i = 0; i < 2; i++) {
            int base = i * 256 + wid * 64;
            int slot = base + lane;
            int row = slot >> 2, cp = slot & 3;
            int c = cp ^ (row & 3);
            g2l16(Bt + Bbase + (long)row * K + k0 + c * 8, &Bs[buf][base * 8]);
        }
    };

    stage(0, 0);
    __syncthreads();

    for (int t = 0; t < 32; t++) {
        const int cur = t & 1;
        if (t + 1 < 32) stage(1 - cur, (t + 1) * 32);
        bf16x8 af[4], bfr[4];
#pragma unroll
        for (int tt = 0; tt < 4; tt++) {
            int ra = wm * 64 + tt * 16 + l15;
            af[tt]  = *(const bf16x8*)(&As[cur][0] + ra * 32 + ((quad ^ (l15 & 3))) * 8);
            int rb = wn * 64 + tt * 16 + l15;
            bfr[tt] = *(const bf16x8*)(&Bs[cur][0] + rb * 32 + ((quad ^ (l15 & 3))) * 8);
        }
#pragma unroll
        for (int tm = 0; tm < 4; tm++)
#pragma unroll
            for (int tn = 0; tn < 4; tn++)
                acc[tm][tn] = __builtin_amdgcn_mfma_f32_16x16x32_bf16(af[tm], bfr[tn], acc[tm][tn], 0, 0, 0);
        __syncthreads();
    }

    const float Cq = 0.125f * 1.44269504f;   // score scale * log2(e), folded into Q
    for (int tm = 0; tm < 4; tm++)
        for (int tn = 0; tn < 4; tn++)
            for (int r = 0; r < 4; r++) {
                int gm = bm * 128 + wm * 64 + tm * 16 + quad * 4 + r;
                int gn = bn * 128 + wn * 64 + tn * 16 + l15;
                float v = acc[tm][tn][r];
                int b = gm >> 11, s = gm & 2047;
                if (gn < 1024) {
                    int h = gn >> 6, d = gn & 63;
                    Qo[(((long)(b * H_ + h) * S_ + s) << 6) + d] = f2bf(v * Cq);
                } else if (gn < 2048) {
                    int g = gn - 1024; int h = g >> 6, d = g & 63;
                    Ko[(((long)(b * H_ + h) * S_ + s) << 6) + d] = f2bf(v * fw[s]);
                } else {
                    int g = gn - 2048; int h = g >> 6, d = g & 63;
                    union { _Float16 h; unsigned short u; } cv;
                    cv.h = (_Float16)v;                       // V^T stored FP16
                    int sp = s ^ ((d & 8) ? 4 : 0);           // R13 half-swap involution
                    Vt[((long)(b * H_ + h) * DH_ + d) * S_ + sp] = cv.u;
                }
            }
}

// ---------------- 128x64 MFMA GEMM (gemm1 / Wo projection), BK=32 dbuf ----------------
// R15: BN=64 -> 512 blocks. R17: BK=32 dbuf, 24KB LDS -> multi-block/CU.
__global__ __launch_bounds__(256, 2)
void gemm_wo(const unsigned short* __restrict__ A, const unsigned short* __restrict__ Bt,
             float* __restrict__ Cout)
{
    __shared__ __align__(16) unsigned short As[2][128 * 32];
    __shared__ __align__(16) unsigned short Bs[2][64 * 32];
    const int tid  = threadIdx.x;
    const int lane = tid & 63, wid = tid >> 6;
    const int quad = lane >> 4, l15 = lane & 15;
    const int bm = blockIdx.y, bn = blockIdx.x;
    const int K = 1024;
    f32x4 acc[2][4] = {};
    const long Abase = (long)bm * 128 * K;
    const long Bbase = (long)bn * 64 * K;

    auto stage = [&](int buf, int k0) {
#pragma unroll
        for (int i = 0; i < 2; i++) {
            int base = i * 256 + wid * 64;
            int slot = base + lane;
            int row = slot >> 2, cp = slot & 3;
            int c = cp ^ (row & 3);
            g2l16(A + Abase + (long)row * K + k0 + c * 8, &As[buf][base * 8]);
        }
        {
            int base = wid * 64;
            int slot = base + lane;
            int row = slot >> 2, cp = slot & 3;
            int c = cp ^ (row & 3);
            g2l16(Bt + Bbase + (long)row * K + k0 + c * 8, &Bs[buf][base * 8]);
        }
    };

    stage(0, 0);
    __syncthreads();

    for (int t = 0; t < 32; t++) {
        const int cur = t & 1;
        if (t + 1 < 32) stage(1 - cur, (t + 1) * 32);
        bf16x8 af[2], bfr[4];
#pragma unroll
        for (int tt = 0; tt < 2; tt++) {
            int ra = wid * 32 + tt * 16 + l15;
            af[tt]  = *(const bf16x8*)(&As[cur][0] + ra * 32 + ((quad ^ (l15 & 3))) * 8);
        }
#pragma unroll
        for (int tt = 0; tt < 4; tt++) {
            int rb = tt * 16 + l15;
            bfr[tt] = *(const bf16x8*)(&Bs[cur][0] + rb * 32 + ((quad ^ (l15 & 3))) * 8);
        }
#pragma unroll
        for (int tm = 0; tm < 2; tm++)
#pragma unroll
            for (int tn = 0; tn < 4; tn++)
                acc[tm][tn] = __builtin_amdgcn_mfma_f32_16x16x32_bf16(af[tm], bfr[tn], acc[tm][tn], 0, 0, 0);
        __syncthreads();
    }

    for (int tm = 0; tm < 2; tm++)
        for (int tn = 0; tn < 4; tn++)
            for (int r = 0; r < 4; r++) {
                int gm = bm * 128 + wid * 32 + tm * 16 + quad * 4 + r;
                int gn = bn * 64 + tn * 16 + l15;
                Cout[(long)gm * 1024 + gn] = acc[tm][tn][r];
            }
}

// ---------------- flash attention: in-block split-K ----------------
// R14: split-K. Softmax is MAX-FREE (pure exp2, fw sums to 1) => partial
// (O, l) over key halves are DIRECTLY ADDABLE - no rescale. Block = 512 thr
// = 8 waves: waves 0-3 do keys [0,1024), waves 4-7 keys [1024,2048), each
// wave at 32 q-rows (2 strips SHARING K/V fragments). (R16 lesson: 64KB LDS
// = 1 block/CU; the split-K gain was 8 desynced waves in one block.)
// Combine: upper half writes fp32 partial O (+l) into the dead K/V LDS,
// one barrier, lower half adds+normalizes+stores.
// R15: V-fragment preload before exp2 (LDS drains under VALU).
// l via MFMA (R14b). Register-P (R8), PV K=32 f16 key-permutation packing
// (R10), V half-swap bank fix (R13b, conflicts 4.19M -> 0) retained.
__global__ __launch_bounds__(512, 4)
void attn_kernel(const unsigned short* __restrict__ Q, const unsigned short* __restrict__ Kb,
                 const unsigned short* __restrict__ Vt,
                 unsigned short* __restrict__ O)
{
    // [half][buf][K=0/V=1][64*64 shorts] = 64 KB
    __shared__ __align__(16) unsigned short smem[2][2][2][64 * 64];

    const int tid  = threadIdx.x;
    const int lane = tid & 63, wid = tid >> 6;    // wid in {0..7}
    const int half = wid >> 2, sw = wid & 3;      // key-half, sub-wave
    const int quad = lane >> 4, l15 = lane & 15;
    const int bh = blockIdx.y;
    const int qt = blockIdx.x;                    // 128 q-rows per block, 32 per wave

    const unsigned short* Kg = Kb + (long)bh * S_ * DH_;
    const unsigned short* Vg = Vt + (long)bh * (long)DH_ * S_;

    bf16x8 qf[2][2];
#pragma unroll
    for (int st = 0; st < 2; st++) {
        const unsigned short* Qp = Q + ((long)bh * S_ + qt * 128 + sw * 32 + st * 16 + l15) * DH_ + quad * 8;
        qf[st][0] = *(const bf16x8*)(Qp);
        qf[st][1] = *(const bf16x8*)(Qp + 32);
    }

    // stage absolute tile kt into this half's buffer: 512 chunks K + 512 V,
    // 4 sub-waves x 2 rounds each
    auto issue = [&](int buf, int kt) {
#pragma unroll
        for (int i = 0; i < 2; i++) {
            int base = i * 256 + sw * 64;
            int slot = base + lane;
            int row = slot >> 3, cp = slot & 7;
            int c = cp ^ (row & 7);
            g2l16(Kg + ((long)(kt * 64 + row) * 64 + c * 8), &smem[half][buf][0][base * 8]);
        }
#pragma unroll
        for (int i = 0; i < 2; i++) {
            int base = i * 256 + sw * 64;
            int slot = base + lane;
            int row = slot >> 3, cp = slot & 7;
            int c = cp ^ (row & 7);
            g2l16(Vg + ((long)row * S_ + kt * 64 + c * 8), &smem[half][buf][1][base * 8]);
        }
    };

    f32x4 oacc[2][4] = {};
    f32x4 lacc[2] = {};
    const f16x8 vone = {(_Float16)1.f, (_Float16)1.f, (_Float16)1.f, (_Float16)1.f,
                        (_Float16)1.f, (_Float16)1.f, (_Float16)1.f, (_Float16)1.f};

    const int kt0 = half * 16;                    // 16 tiles per half
    issue(0, kt0);
    __syncthreads();

    const int hf = (((quad & 1) ^ ((l15 >> 3) & 1))) * 4;   // R13b bank fix

    for (int t = 0; t < 16; t++) {
        const int cur = t & 1;
        if (t + 1 < 16) issue(1 - cur, kt0 + t + 1);

        const unsigned short* Kc = &smem[half][cur][0][0];
        const unsigned short* Vc = &smem[half][cur][1][0];

        // ---- S^T tiles: mfma(K_frag, Q_frag) -> [key=quad*4+r][q=l15] ----
        f32x4 sacc[2][4] = {};
#pragma unroll
        for (int kc = 0; kc < 4; kc++) {
            int row = kc * 16 + l15;
            bf16x8 k0 = *(const bf16x8*)(Kc + (row * 8 + (quad       ^ (l15 & 7))) * 8);
            bf16x8 k1 = *(const bf16x8*)(Kc + (row * 8 + ((4 + quad) ^ (l15 & 7))) * 8);
#pragma unroll
            for (int st = 0; st < 2; st++) {
                sacc[st][kc] = __builtin_amdgcn_mfma_f32_16x16x32_bf16(k0, qf[st][0], sacc[st][kc], 0, 0, 0);
                sacc[st][kc] = __builtin_amdgcn_mfma_f32_16x16x32_bf16(k1, qf[st][1], sacc[st][kc], 0, 0, 0);
            }
        }

        // ---- R15: preload ALL V fragments now; LDS drains under exp2 ----
        f16x8 vfr[2][4];
#pragma unroll
        for (int c = 0; c < 2; c++)
#pragma unroll
            for (int dt = 0; dt < 4; dt++) {
                int row = dt * 16 + l15;
                int p0 = (c * 4 +     (quad >> 1)) ^ (l15 & 7);
                int p1 = (c * 4 + 2 + (quad >> 1)) ^ (l15 & 7);
                f16x4 v0 = *(const f16x4*)(Vc + row * 64 + p0 * 8 + hf);
                f16x4 v1 = *(const f16x4*)(Vc + row * 64 + p1 * 8 + hf);
                vfr[c][dt] = __builtin_shufflevector(v0, v1, 0, 1, 2, 3, 4, 5, 6, 7);
            }

        // ---- p = 2^sacc packed into K=32 f16 PV A-fragments (R10 bijection) ----
        f16x8 pk8[2][2];
#pragma unroll
        for (int st = 0; st < 2; st++)
#pragma unroll
            for (int c = 0; c < 2; c++) {
                union { uint4 u; f16x8 v; } pku;
#pragma unroll
                for (int hh = 0; hh < 2; hh++) {
                    float p0 = __builtin_amdgcn_exp2f(sacc[st][2 * c + hh][0]);
                    float p1 = __builtin_amdgcn_exp2f(sacc[st][2 * c + hh][1]);
                    float p2 = __builtin_amdgcn_exp2f(sacc[st][2 * c + hh][2]);
                    float p3 = __builtin_amdgcn_exp2f(sacc[st][2 * c + hh][3]);
                    union { fp16x2 h2; unsigned int u; } a, b;
                    a.h2 = __builtin_amdgcn_cvt_pkrtz(p0, p1);
                    b.h2 = __builtin_amdgcn_cvt_pkrtz(p2, p3);
                    if (hh == 0) { pku.u.x = a.u; pku.u.y = b.u; }
                    else         { pku.u.z = a.u; pku.u.w = b.u; }
                }
                pk8[st][c] = pku.v;
            }

        // ---- O += P V (K=32 f16) all-register; l += P . 1 via MFMA ----
#pragma unroll
        for (int c = 0; c < 2; c++) {
            lacc[0] = __builtin_amdgcn_mfma_f32_16x16x32_f16(pk8[0][c], vone, lacc[0], 0, 0, 0);
            lacc[1] = __builtin_amdgcn_mfma_f32_16x16x32_f16(pk8[1][c], vone, lacc[1], 0, 0, 0);
#pragma unroll
            for (int dt = 0; dt < 4; dt++) {
                oacc[0][dt] = __builtin_amdgcn_mfma_f32_16x16x32_f16(pk8[0][c], vfr[c][dt], oacc[0][dt], 0, 0, 0);
                oacc[1][dt] = __builtin_amdgcn_mfma_f32_16x16x32_f16(pk8[1][c], vfr[c][dt], oacc[1][dt], 0, 0, 0);
            }
        }

        __syncthreads();
    }
    // loop ends with a full barrier: all LDS K/V reads complete -> overlay safe

    // combine overlay over the dead K/V LDS: 128 x stride-66 fp32 O + 128 fp32 l
    float* ov = (float*)&smem[0][0][0][0];
    float* lv = ov + 128 * 66;

    if (half == 1) {
#pragma unroll
        for (int st = 0; st < 2; st++) {
#pragma unroll
            for (int dt = 0; dt < 4; dt++)
#pragma unroll
                for (int r = 0; r < 4; r++) {
                    int qr = sw * 32 + st * 16 + quad * 4 + r;
                    ov[qr * 66 + dt * 16 + l15] = oacc[st][dt][r];
                }
            if (l15 == 0) {
#pragma unroll
                for (int r = 0; r < 4; r++)
                    lv[sw * 32 + st * 16 + quad * 4 + r] = lacc[st][r];
            }
        }
    }
    __syncthreads();

    if (half == 0) {
        int b = bh >> 4, h = bh & 15;
#pragma unroll
        for (int st = 0; st < 2; st++)
#pragma unroll
            for (int r = 0; r < 4; r++) {
                int qr = sw * 32 + st * 16 + quad * 4 + r;
                float inv = 1.0f / (lacc[st][r] + lv[qr]);
                int srow = qt * 128 + qr;
#pragma unroll
                for (int dt = 0; dt < 4; dt++) {
                    float val = oacc[st][dt][r] + ov[qr * 66 + dt * 16 + l15];
                    O[((long)(b * S_ + srow)) * 1024 + h * DH_ + dt * 16 + l15] = f2bf(val * inv);
                }
            }
    }
}

// ---------------- launch ----------------

extern "C" void kernel_launch(void* const* d_in, const int* in_sizes, int n_in,
                              void* d_out, int out_size, void* d_ws, size_t ws_size,
                              hipStream_t stream)
{
    const float* x  = (const float*)d_in[0];
    const float* Wq = (const float*)d_in[1];
    const float* Wk = (const float*)d_in[2];
    const float* Wv = (const float*)d_in[3];
    const float* Wo = (const float*)d_in[4];
    const float* fw = (const float*)d_in[5];
    float* out = (float*)d_out;

    char* ws = (char*)d_ws;
    unsigned short* xb    = (unsigned short*)(ws);               // 8 MB   [B*S, D] bf16
    unsigned short* WqkvT = (unsigned short*)(ws + 8388608);     // 6 MB   [3072,1024] bf16
    unsigned short* WoT   = (unsigned short*)(ws + 14680064);    // 2 MB   [1024,1024] bf16
    unsigned short* Qb    = (unsigned short*)(ws + 16777216);    // 8 MB   [B,H,S,64] bf16 (pre-scaled Cq)
    unsigned short* Kb    = (unsigned short*)(ws + 25165824);    // 8 MB   [B,H,S,64] bf16 (pre-scaled fw)
    unsigned short* Vt    = (unsigned short*)(ws + 33554432);    // 8 MB   [B,H,64,S] fp16 (half-swapped)
    unsigned short* Ob    = xb;                                  // alias: xb dead after gemm1

    convert_x<<<dim3((B_ * S_ * D_) / 4 / 256), dim3(256), 0, stream>>>(x, xb, B_ * S_ * D_);
    transpose_w<<<dim3(32, 32, 4), dim3(32, 8), 0, stream>>>(
        Wq, Wk, Wv, Wo,
        WqkvT, WqkvT + 1024 * 1024, WqkvT + 2 * 1024 * 1024, WoT);
    gemm128<<<dim3(24, 32), dim3(256), 0, stream>>>(xb, WqkvT, Qb, Kb, Vt, fw);
    attn_kernel<<<dim3(S_ / 128, B_ * H_), dim3(512), 0, stream>>>(Qb, Kb, Vt, Ob);
    gemm_wo<<<dim3(16, 32), dim3(256), 0, stream>>>(Ob, WoT, out);
}

// Round 9
// 190.045 us; speedup vs baseline: 1.0701x; 1.0334x over previous
//
#include <hip/hip_runtime.h>
#include <hip/hip_bf16.h>
#include <stdint.h>

#define B_  2
#define S_  2048
#define D_  1024
#define H_  16
#define DH_ 64

typedef __attribute__((ext_vector_type(8))) __bf16    bf16x8;
typedef __attribute__((ext_vector_type(8))) _Float16  f16x8;
typedef __attribute__((ext_vector_type(4))) _Float16  f16x4;
typedef __attribute__((ext_vector_type(2))) __fp16    fp16x2;   // cvt_pkrtz return type
typedef __attribute__((ext_vector_type(4))) float     f32x4;

__device__ inline unsigned short f2bf(float f) {
    union { float f; uint32_t u; } v; v.f = f;
    uint32_t r = (v.u + 0x7fffu + ((v.u >> 16) & 1u)) >> 16;
    return (unsigned short)r;
}

// async global->LDS, 16B per lane. LDS dest = wave-uniform base + lane*16.
__device__ __forceinline__ void g2l16(const unsigned short* g, unsigned short* l) {
    __builtin_amdgcn_global_load_lds(
        (const __attribute__((address_space(1))) unsigned int*)g,
        (__attribute__((address_space(3))) unsigned int*)l,
        16, 0, 0);
}

// ---------------- conversion kernels ----------------

__global__ void convert_x(const float* __restrict__ x, unsigned short* __restrict__ xb, int n) {
    int i = (blockIdx.x * blockDim.x + threadIdx.x) * 4;
    if (i < n) {
        float4 v = *(const float4*)(x + i);
        ushort4 o;
        o.x = f2bf(v.x); o.y = f2bf(v.y); o.z = f2bf(v.z); o.w = f2bf(v.w);
        *(ushort4*)(xb + i) = o;
    }
}

// transpose+convert 1024x1024 fp32 [K][N] -> bf16 [N][K]; z selects matrix
__global__ void transpose_w(const float* __restrict__ s0, const float* __restrict__ s1,
                            const float* __restrict__ s2, const float* __restrict__ s3,
                            unsigned short* __restrict__ d0, unsigned short* __restrict__ d1,
                            unsigned short* __restrict__ d2, unsigned short* __restrict__ d3) {
    __shared__ float tile[32][33];
    const float* src; unsigned short* dst;
    switch (blockIdx.z) {
        case 0: src = s0; dst = d0; break;
        case 1: src = s1; dst = d1; break;
        case 2: src = s2; dst = d2; break;
        default: src = s3; dst = d3; break;
    }
    int n0 = blockIdx.x * 32, k0 = blockIdx.y * 32;
    int tx = threadIdx.x, ty = threadIdx.y;   // (32, 8)
    for (int j = 0; j < 32; j += 8)
        tile[ty + j][tx] = src[(long)(k0 + ty + j) * 1024 + n0 + tx];
    __syncthreads();
    for (int j = 0; j < 32; j += 8)
        dst[(long)(n0 + ty + j) * 1024 + k0 + tx] = f2bf(tile[tx][ty + j]);
}

// ---------------- 128x64 MFMA GEMM (gemm0), single-buffer BK=64 ----------------
// R18: gemm0 experiment chain: single-BK64 52.7us (BEST) / dbuf-BK64 60.7 /
// dbuf-BK32 62.6. Source-level dbuf CANNOT win: __syncthreads() emits
// s_waitcnt vmcnt(0) which drains the just-issued prefetch (the documented
// barrier-drain ceiling). REVERT to single-buffer; attack the untested axis:
// grid 768 blocks = 3 blocks/CU was the occupancy binding limit (30% cap,
// 69% idle, latency-bound). Retile N 128->64: grid (48,32) = 1536 blocks =
// up to 6 blocks/CU (LDS 24KB), >=16 waves/CU. Same proven staging/swizzle.
// Scatter epilogue -> Q bf16 (PRE-SCALED 0.125*log2e), K bf16 (PRE-SCALED
// fw[s]), Vt[B,H,64,S] fp16 with half-swap s^((d&8)?4:0) (R13 attn bank fix).
// Q/K/V regions are bn-uniform (boundaries at multiples of 64).
__global__ __launch_bounds__(256, 4)
void gemm128(const unsigned short* __restrict__ A, const unsigned short* __restrict__ Bt,
             unsigned short* __restrict__ Qo, unsigned short* __restrict__ Ko,
             unsigned short* __restrict__ Vt,
             const float* __restrict__ fw)
{
    __shared__ __align__(16) unsigned short As[128 * 64];
    __shared__ __align__(16) unsigned short Bs[64 * 64];
    const int tid  = threadIdx.x;
    const int lane = tid & 63, wid = tid >> 6;
    const int quad = lane >> 4, l15 = lane & 15;
    const int bm = blockIdx.y, bn = blockIdx.x;
    const int K = 1024;
    f32x4 acc[2][4] = {};
    const long Abase = (long)bm * 128 * K;
    const long Bbase = (long)bn * 64 * K;

    for (int k0 = 0; k0 < K; k0 += 64) {
        __syncthreads();
        // A: 128x64 = 1024 chunks of 16B, 4 rounds
#pragma unroll
        for (int i = 0; i < 4; i++) {
            int base = i * 256 + wid * 64;
            int slot = base + lane;
            int row = slot >> 3, cp = slot & 7;
            int c = cp ^ (row & 7);
            g2l16(A + Abase + (long)row * K + k0 + c * 8, &As[base * 8]);
        }
        // B: 64x64 = 512 chunks, 2 rounds
#pragma unroll
        for (int i = 0; i < 2; i++) {
            int base = i * 256 + wid * 64;
            int slot = base + lane;
            int row = slot >> 3, cp = slot & 7;
            int c = cp ^ (row & 7);
            g2l16(Bt + Bbase + (long)row * K + k0 + c * 8, &Bs[base * 8]);
        }
        __syncthreads();
#pragma unroll
        for (int ks = 0; ks < 2; ks++) {
            bf16x8 af[2], bfr[4];
#pragma unroll
            for (int tt = 0; tt < 2; tt++) {
                int ra = wid * 32 + tt * 16 + l15;
                af[tt]  = *(const bf16x8*)(As + ra * 64 + (((ks * 4 + quad) ^ (l15 & 7))) * 8);
            }
#pragma unroll
            for (int tt = 0; tt < 4; tt++) {
                int rb = tt * 16 + l15;
                bfr[tt] = *(const bf16x8*)(Bs + rb * 64 + (((ks * 4 + quad) ^ (l15 & 7))) * 8);
            }
#pragma unroll
            for (int tm = 0; tm < 2; tm++)
#pragma unroll
                for (int tn = 0; tn < 4; tn++)
                    acc[tm][tn] = __builtin_amdgcn_mfma_f32_16x16x32_bf16(af[tm], bfr[tn], acc[tm][tn], 0, 0, 0);
        }
    }

    const float Cq = 0.125f * 1.44269504f;   // score scale * log2(e), folded into Q
    for (int tm = 0; tm < 2; tm++)
        for (int tn = 0; tn < 4; tn++)
            for (int r = 0; r < 4; r++) {
                int gm = bm * 128 + wid * 32 + tm * 16 + quad * 4 + r;
                int gn = bn * 64 + tn * 16 + l15;
                float v = acc[tm][tn][r];
                int b = gm >> 11, s = gm & 2047;
                if (gn < 1024) {
                    int h = gn >> 6, d = gn & 63;
                    Qo[(((long)(b * H_ + h) * S_ + s) << 6) + d] = f2bf(v * Cq);
                } else if (gn < 2048) {
                    int g = gn - 1024; int h = g >> 6, d = g & 63;
                    Ko[(((long)(b * H_ + h) * S_ + s) << 6) + d] = f2bf(v * fw[s]);
                } else {
                    int g = gn - 2048; int h = g >> 6, d = g & 63;
                    union { _Float16 h; unsigned short u; } cv;
                    cv.h = (_Float16)v;                       // V^T stored FP16
                    int sp = s ^ ((d & 8) ? 4 : 0);           // R13 half-swap involution
                    Vt[((long)(b * H_ + h) * DH_ + d) * S_ + sp] = cv.u;
                }
            }
}

// ---------------- 64x64 MFMA GEMM (gemm1 / Wo projection), single-buffer ----------------
// R18: same occupancy lever: 64x64 tile -> grid (16,64) = 1024 blocks =
// 4+ blocks/CU, 16 waves/CU (was 512 blocks = 2/CU = 8 waves). LDS 16KB.
__global__ __launch_bounds__(256, 4)
void gemm_wo(const unsigned short* __restrict__ A, const unsigned short* __restrict__ Bt,
             float* __restrict__ Cout)
{
    __shared__ __align__(16) unsigned short As[64 * 64];
    __shared__ __align__(16) unsigned short Bs[64 * 64];
    const int tid  = threadIdx.x;
    const int lane = tid & 63, wid = tid >> 6;
    const int quad = lane >> 4, l15 = lane & 15;
    const int bm = blockIdx.y, bn = blockIdx.x;
    const int K = 1024;
    f32x4 acc[4] = {};
    const long Abase = (long)bm * 64 * K;
    const long Bbase = (long)bn * 64 * K;

    for (int k0 = 0; k0 < K; k0 += 64) {
        __syncthreads();
#pragma unroll
        for (int i = 0; i < 2; i++) {
            int base = i * 256 + wid * 64;
            int slot = base + lane;
            int row = slot >> 3, cp = slot & 7;
            int c = cp ^ (row & 7);
            g2l16(A + Abase + (long)row * K + k0 + c * 8, &As[base * 8]);
        }
#pragma unroll
        for (int i = 0; i < 2; i++) {
            int base = i * 256 + wid * 64;
            int slot = base + lane;
            int row = slot >> 3, cp = slot & 7;
            int c = cp ^ (row & 7);
            g2l16(Bt + Bbase + (long)row * K + k0 + c * 8, &Bs[base * 8]);
        }
        __syncthreads();
#pragma unroll
        for (int ks = 0; ks < 2; ks++) {
            bf16x8 af, bfr[4];
            {
                int ra = wid * 16 + l15;
                af = *(const bf16x8*)(As + ra * 64 + (((ks * 4 + quad) ^ (l15 & 7))) * 8);
            }
#pragma unroll
            for (int tt = 0; tt < 4; tt++) {
                int rb = tt * 16 + l15;
                bfr[tt] = *(const bf16x8*)(Bs + rb * 64 + (((ks * 4 + quad) ^ (l15 & 7))) * 8);
            }
#pragma unroll
            for (int tn = 0; tn < 4; tn++)
                acc[tn] = __builtin_amdgcn_mfma_f32_16x16x32_bf16(af, bfr[tn], acc[tn], 0, 0, 0);
        }
    }

    for (int tn = 0; tn < 4; tn++)
        for (int r = 0; r < 4; r++) {
            int gm = bm * 64 + wid * 16 + quad * 4 + r;
            int gn = bn * 64 + tn * 16 + l15;
            Cout[(long)gm * 1024 + gn] = acc[tn][r];
        }
}

// ---------------- flash attention: in-block split-K ----------------
// R14: split-K. Softmax is MAX-FREE (pure exp2, fw sums to 1) => partial
// (O, l) over key halves are DIRECTLY ADDABLE - no rescale. Block = 512 thr
// = 8 waves: waves 0-3 do keys [0,1024), waves 4-7 keys [1024,2048), each
// wave at 32 q-rows (2 strips SHARING K/V fragments).
// Combine: upper half writes fp32 partial O (+l) into the dead K/V LDS,
// one barrier, lower half adds+normalizes+stores.
// R15: V-fragment preload before exp2 (LDS drains under VALU).
// l via MFMA (R14b). Register-P (R8), PV K=32 f16 key-permutation packing
// (R10), V half-swap bank fix (R13b, conflicts 4.19M -> 0) retained.
__global__ __launch_bounds__(512, 4)
void attn_kernel(const unsigned short* __restrict__ Q, const unsigned short* __restrict__ Kb,
                 const unsigned short* __restrict__ Vt,
                 unsigned short* __restrict__ O)
{
    // [half][buf][K=0/V=1][64*64 shorts] = 64 KB
    __shared__ __align__(16) unsigned short smem[2][2][2][64 * 64];

    const int tid  = threadIdx.x;
    const int lane = tid & 63, wid = tid >> 6;    // wid in {0..7}
    const int half = wid >> 2, sw = wid & 3;      // key-half, sub-wave
    const int quad = lane >> 4, l15 = lane & 15;
    const int bh = blockIdx.y;
    const int qt = blockIdx.x;                    // 128 q-rows per block, 32 per wave

    const unsigned short* Kg = Kb + (long)bh * S_ * DH_;
    const unsigned short* Vg = Vt + (long)bh * (long)DH_ * S_;

    bf16x8 qf[2][2];
#pragma unroll
    for (int st = 0; st < 2; st++) {
        const unsigned short* Qp = Q + ((long)bh * S_ + qt * 128 + sw * 32 + st * 16 + l15) * DH_ + quad * 8;
        qf[st][0] = *(const bf16x8*)(Qp);
        qf[st][1] = *(const bf16x8*)(Qp + 32);
    }

    // stage absolute tile kt into this half's buffer: 512 chunks K + 512 V,
    // 4 sub-waves x 2 rounds each
    auto issue = [&](int buf, int kt) {
#pragma unroll
        for (int i = 0; i < 2; i++) {
            int base = i * 256 + sw * 64;
            int slot = base + lane;
            int row = slot >> 3, cp = slot & 7;
            int c = cp ^ (row & 7);
            g2l16(Kg + ((long)(kt * 64 + row) * 64 + c * 8), &smem[half][buf][0][base * 8]);
        }
#pragma unroll
        for (int i = 0; i < 2; i++) {
            int base = i * 256 + sw * 64;
            int slot = base + lane;
            int row = slot >> 3, cp = slot & 7;
            int c = cp ^ (row & 7);
            g2l16(Vg + ((long)row * S_ + kt * 64 + c * 8), &smem[half][buf][1][base * 8]);
        }
    };

    f32x4 oacc[2][4] = {};
    f32x4 lacc[2] = {};
    const f16x8 vone = {(_Float16)1.f, (_Float16)1.f, (_Float16)1.f, (_Float16)1.f,
                        (_Float16)1.f, (_Float16)1.f, (_Float16)1.f, (_Float16)1.f};

    const int kt0 = half * 16;                    // 16 tiles per half
    issue(0, kt0);
    __syncthreads();

    const int hf = (((quad & 1) ^ ((l15 >> 3) & 1))) * 4;   // R13b bank fix

    for (int t = 0; t < 16; t++) {
        const int cur = t & 1;
        if (t + 1 < 16) issue(1 - cur, kt0 + t + 1);

        const unsigned short* Kc = &smem[half][cur][0][0];
        const unsigned short* Vc = &smem[half][cur][1][0];

        // ---- S^T tiles: mfma(K_frag, Q_frag) -> [key=quad*4+r][q=l15] ----
        f32x4 sacc[2][4] = {};
#pragma unroll
        for (int kc = 0; kc < 4; kc++) {
            int row = kc * 16 + l15;
            bf16x8 k0 = *(const bf16x8*)(Kc + (row * 8 + (quad       ^ (l15 & 7))) * 8);
            bf16x8 k1 = *(const bf16x8*)(Kc + (row * 8 + ((4 + quad) ^ (l15 & 7))) * 8);
#pragma unroll
            for (int st = 0; st < 2; st++) {
                sacc[st][kc] = __builtin_amdgcn_mfma_f32_16x16x32_bf16(k0, qf[st][0], sacc[st][kc], 0, 0, 0);
                sacc[st][kc] = __builtin_amdgcn_mfma_f32_16x16x32_bf16(k1, qf[st][1], sacc[st][kc], 0, 0, 0);
            }
        }

        // ---- R15: preload ALL V fragments now; LDS drains under exp2 ----
        f16x8 vfr[2][4];
#pragma unroll
        for (int c = 0; c < 2; c++)
#pragma unroll
            for (int dt = 0; dt < 4; dt++) {
                int row = dt * 16 + l15;
                int p0 = (c * 4 +     (quad >> 1)) ^ (l15 & 7);
                int p1 = (c * 4 + 2 + (quad >> 1)) ^ (l15 & 7);
                f16x4 v0 = *(const f16x4*)(Vc + row * 64 + p0 * 8 + hf);
                f16x4 v1 = *(const f16x4*)(Vc + row * 64 + p1 * 8 + hf);
                vfr[c][dt] = __builtin_shufflevector(v0, v1, 0, 1, 2, 3, 4, 5, 6, 7);
            }

        // ---- p = 2^sacc packed into K=32 f16 PV A-fragments (R10 bijection) ----
        f16x8 pk8[2][2];
#pragma unroll
        for (int st = 0; st < 2; st++)
#pragma unroll
            for (int c = 0; c < 2; c++) {
                union { uint4 u; f16x8 v; } pku;
#pragma unroll
                for (int hh = 0; hh < 2; hh++) {
                    float p0 = __builtin_amdgcn_exp2f(sacc[st][2 * c + hh][0]);
                    float p1 = __builtin_amdgcn_exp2f(sacc[st][2 * c + hh][1]);
                    float p2 = __builtin_amdgcn_exp2f(sacc[st][2 * c + hh][2]);
                    float p3 = __builtin_amdgcn_exp2f(sacc[st][2 * c + hh][3]);
                    union { fp16x2 h2; unsigned int u; } a, b;
                    a.h2 = __builtin_amdgcn_cvt_pkrtz(p0, p1);
                    b.h2 = __builtin_amdgcn_cvt_pkrtz(p2, p3);
                    if (hh == 0) { pku.u.x = a.u; pku.u.y = b.u; }
                    else         { pku.u.z = a.u; pku.u.w = b.u; }
                }
                pk8[st][c] = pku.v;
            }

        // ---- O += P V (K=32 f16) all-register; l += P . 1 via MFMA ----
#pragma unroll
        for (int c = 0; c < 2; c++) {
            lacc[0] = __builtin_amdgcn_mfma_f32_16x16x32_f16(pk8[0][c], vone, lacc[0], 0, 0, 0);
            lacc[1] = __builtin_amdgcn_mfma_f32_16x16x32_f16(pk8[1][c], vone, lacc[1], 0, 0, 0);
#pragma unroll
            for (int dt = 0; dt < 4; dt++) {
                oacc[0][dt] = __builtin_amdgcn_mfma_f32_16x16x32_f16(pk8[0][c], vfr[c][dt], oacc[0][dt], 0, 0, 0);
                oacc[1][dt] = __builtin_amdgcn_mfma_f32_16x16x32_f16(pk8[1][c], vfr[c][dt], oacc[1][dt], 0, 0, 0);
            }
        }

        __syncthreads();
    }
    // loop ends with a full barrier: all LDS K/V reads complete -> overlay safe

    // combine overlay over the dead K/V LDS: 128 x stride-66 fp32 O + 128 fp32 l
    float* ov = (float*)&smem[0][0][0][0];
    float* lv = ov + 128 * 66;

    if (half == 1) {
#pragma unroll
        for (int st = 0; st < 2; st++) {
#pragma unroll
            for (int dt = 0; dt < 4; dt++)
#pragma unroll
                for (int r = 0; r < 4; r++) {
                    int qr = sw * 32 + st * 16 + quad * 4 + r;
                    ov[qr * 66 + dt * 16 + l15] = oacc[st][dt][r];
                }
            if (l15 == 0) {
#pragma unroll
                for (int r = 0; r < 4; r++)
                    lv[sw * 32 + st * 16 + quad * 4 + r] = lacc[st][r];
            }
        }
    }
    __syncthreads();

    if (half == 0) {
        int b = bh >> 4, h = bh & 15;
#pragma unroll
        for (int st = 0; st < 2; st++)
#pragma unroll
            for (int r = 0; r < 4; r++) {
                int qr = sw * 32 + st * 16 + quad * 4 + r;
                float inv = 1.0f / (lacc[st][r] + lv[qr]);
                int srow = qt * 128 + qr;
#pragma unroll
                for (int dt = 0; dt < 4; dt++) {
                    float val = oacc[st][dt][r] + ov[qr * 66 + dt * 16 + l15];
                    O[((long)(b * S_ + srow)) * 1024 + h * DH_ + dt * 16 + l15] = f2bf(val * inv);
                }
            }
    }
}

// ---------------- launch ----------------

extern "C" void kernel_launch(void* const* d_in, const int* in_sizes, int n_in,
                              void* d_out, int out_size, void* d_ws, size_t ws_size,
                              hipStream_t stream)
{
    const float* x  = (const float*)d_in[0];
    const float* Wq = (const float*)d_in[1];
    const float* Wk = (const float*)d_in[2];
    const float* Wv = (const float*)d_in[3];
    const float* Wo = (const float*)d_in[4];
    const float* fw = (const float*)d_in[5];
    float* out = (float*)d_out;

    char* ws = (char*)d_ws;
    unsigned short* xb    = (unsigned short*)(ws);               // 8 MB   [B*S, D] bf16
    unsigned short* WqkvT = (unsigned short*)(ws + 8388608);     // 6 MB   [3072,1024] bf16
    unsigned short* WoT   = (unsigned short*)(ws + 14680064);    // 2 MB   [1024,1024] bf16
    unsigned short* Qb    = (unsigned short*)(ws + 16777216);    // 8 MB   [B,H,S,64] bf16 (pre-scaled Cq)
    unsigned short* Kb    = (unsigned short*)(ws + 25165824);    // 8 MB   [B,H,S,64] bf16 (pre-scaled fw)
    unsigned short* Vt    = (unsigned short*)(ws + 33554432);    // 8 MB   [B,H,64,S] fp16 (half-swapped)
    unsigned short* Ob    = xb;                                  // alias: xb dead after gemm1

    convert_x<<<dim3((B_ * S_ * D_) / 4 / 256), dim3(256), 0, stream>>>(x, xb, B_ * S_ * D_);
    transpose_w<<<dim3(32, 32, 4), dim3(32, 8), 0, stream>>>(
        Wq, Wk, Wv, Wo,
        WqkvT, WqkvT + 1024 * 1024, WqkvT + 2 * 1024 * 1024, WoT);
    gemm128<<<dim3(48, 32), dim3(256), 0, stream>>>(xb, WqkvT, Qb, Kb, Vt, fw);
    attn_kernel<<<dim3(S_ / 128, B_ * H_), dim3(512), 0, stream>>>(Qb, Kb, Vt, Ob);
    gemm_wo<<<dim3(16, 64), dim3(256), 0, stream>>>(Ob, WoT, out);
}

// Round 10
// 180.112 us; speedup vs baseline: 1.1291x; 1.0552x over previous
//
#include <hip/hip_runtime.h>
#include <hip/hip_bf16.h>
#include <stdint.h>

#define B_  2
#define S_  2048
#define D_  1024
#define H_  16
#define DH_ 64

typedef __attribute__((ext_vector_type(8))) __bf16    bf16x8;
typedef __attribute__((ext_vector_type(8))) _Float16  f16x8;
typedef __attribute__((ext_vector_type(4))) _Float16  f16x4;
typedef __attribute__((ext_vector_type(2))) __fp16    fp16x2;   // cvt_pkrtz return type
typedef __attribute__((ext_vector_type(4))) float     f32x4;

__device__ inline unsigned short f2bf(float f) {
    union { float f; uint32_t u; } v; v.f = f;
    uint32_t r = (v.u + 0x7fffu + ((v.u >> 16) & 1u)) >> 16;
    return (unsigned short)r;
}

// async global->LDS, 16B per lane. LDS dest = wave-uniform base + lane*16.
__device__ __forceinline__ void g2l16(const unsigned short* g, unsigned short* l) {
    __builtin_amdgcn_global_load_lds(
        (const __attribute__((address_space(1))) unsigned int*)g,
        (__attribute__((address_space(3))) unsigned int*)l,
        16, 0, 0);
}

// ---------------- conversion kernels ----------------

__global__ void convert_x(const float* __restrict__ x, unsigned short* __restrict__ xb, int n) {
    int i = (blockIdx.x * blockDim.x + threadIdx.x) * 4;
    if (i < n) {
        float4 v = *(const float4*)(x + i);
        ushort4 o;
        o.x = f2bf(v.x); o.y = f2bf(v.y); o.z = f2bf(v.z); o.w = f2bf(v.w);
        *(ushort4*)(xb + i) = o;
    }
}

// transpose+convert 1024x1024 fp32 [K][N] -> bf16 [N][K]; z selects matrix
__global__ void transpose_w(const float* __restrict__ s0, const float* __restrict__ s1,
                            const float* __restrict__ s2, const float* __restrict__ s3,
                            unsigned short* __restrict__ d0, unsigned short* __restrict__ d1,
                            unsigned short* __restrict__ d2, unsigned short* __restrict__ d3) {
    __shared__ float tile[32][33];
    const float* src; unsigned short* dst;
    switch (blockIdx.z) {
        case 0: src = s0; dst = d0; break;
        case 1: src = s1; dst = d1; break;
        case 2: src = s2; dst = d2; break;
        default: src = s3; dst = d3; break;
    }
    int n0 = blockIdx.x * 32, k0 = blockIdx.y * 32;
    int tx = threadIdx.x, ty = threadIdx.y;   // (32, 8)
    for (int j = 0; j < 32; j += 8)
        tile[ty + j][tx] = src[(long)(k0 + ty + j) * 1024 + n0 + tx];
    __syncthreads();
    for (int j = 0; j < 32; j += 8)
        dst[(long)(n0 + ty + j) * 1024 + k0 + tx] = f2bf(tile[tx][ty + j]);
}

// ---------------- 128x128 MFMA GEMM (gemm0), single-buffer BK=64 ----------------
// R19: gemm0 experiment matrix COMPLETE: single-BK64-128x128 = 52.7us (BEST),
// dbuf-BK64 = 60.7, dbuf-BK32 = 62.6 (+4-way l15 alias conflicts), retile
// 128x64 = 58-62 (halved MFMA/staged-byte, doubled A re-fetch). REVERTED to
// the proven best config. Further gemm0 work would need an 8-phase counted-
// vmcnt 256^2 rewrite - poorly matched to this shape (192 blocks < 256 CU).
// Scatter epilogue -> Q bf16 (PRE-SCALED 0.125*log2e), K bf16 (PRE-SCALED
// fw[s]), Vt[B,H,64,S] fp16 with half-swap s^((d&8)?4:0) (R13 attn bank fix).
__global__ __launch_bounds__(256, 2)
void gemm128(const unsigned short* __restrict__ A, const unsigned short* __restrict__ Bt,
             unsigned short* __restrict__ Qo, unsigned short* __restrict__ Ko,
             unsigned short* __restrict__ Vt,
             const float* __restrict__ fw)
{
    __shared__ __align__(16) unsigned short As[128 * 64];
    __shared__ __align__(16) unsigned short Bs[128 * 64];
    const int tid  = threadIdx.x;
    const int lane = tid & 63, wid = tid >> 6;
    const int quad = lane >> 4, l15 = lane & 15;
    const int wm = wid >> 1, wn = wid & 1;
    const int bm = blockIdx.y, bn = blockIdx.x;
    const int K = 1024;
    f32x4 acc[4][4] = {};
    const long Abase = (long)bm * 128 * K;
    const long Bbase = (long)bn * 128 * K;

    for (int k0 = 0; k0 < K; k0 += 64) {
        __syncthreads();
#pragma unroll
        for (int i = 0; i < 4; i++) {
            int slot = i * 256 + wid * 64 + lane;
            int row = slot >> 3, cp = slot & 7;
            int c = cp ^ (row & 7);
            g2l16(A + Abase + (long)row * K + k0 + c * 8, &As[(i * 256 + wid * 64) * 8]);
        }
#pragma unroll
        for (int i = 0; i < 4; i++) {
            int slot = i * 256 + wid * 64 + lane;
            int row = slot >> 3, cp = slot & 7;
            int c = cp ^ (row & 7);
            g2l16(Bt + Bbase + (long)row * K + k0 + c * 8, &Bs[(i * 256 + wid * 64) * 8]);
        }
        __syncthreads();
#pragma unroll
        for (int ks = 0; ks < 2; ks++) {
            bf16x8 af[4], bfr[4];
#pragma unroll
            for (int t = 0; t < 4; t++) {
                int ra = wm * 64 + t * 16 + l15;
                af[t]  = *(const bf16x8*)(As + ra * 64 + (((ks * 4 + quad) ^ (l15 & 7))) * 8);
                int rb = wn * 64 + t * 16 + l15;
                bfr[t] = *(const bf16x8*)(Bs + rb * 64 + (((ks * 4 + quad) ^ (l15 & 7))) * 8);
            }
#pragma unroll
            for (int tm = 0; tm < 4; tm++)
#pragma unroll
                for (int tn = 0; tn < 4; tn++)
                    acc[tm][tn] = __builtin_amdgcn_mfma_f32_16x16x32_bf16(af[tm], bfr[tn], acc[tm][tn], 0, 0, 0);
        }
    }

    const float Cq = 0.125f * 1.44269504f;   // score scale * log2(e), folded into Q
    for (int tm = 0; tm < 4; tm++)
        for (int tn = 0; tn < 4; tn++)
            for (int r = 0; r < 4; r++) {
                int gm = bm * 128 + wm * 64 + tm * 16 + quad * 4 + r;
                int gn = bn * 128 + wn * 64 + tn * 16 + l15;
                float v = acc[tm][tn][r];
                int b = gm >> 11, s = gm & 2047;
                if (gn < 1024) {
                    int h = gn >> 6, d = gn & 63;
                    Qo[(((long)(b * H_ + h) * S_ + s) << 6) + d] = f2bf(v * Cq);
                } else if (gn < 2048) {
                    int g = gn - 1024; int h = g >> 6, d = g & 63;
                    Ko[(((long)(b * H_ + h) * S_ + s) << 6) + d] = f2bf(v * fw[s]);
                } else {
                    int g = gn - 2048; int h = g >> 6, d = g & 63;
                    union { _Float16 h; unsigned short u; } cv;
                    cv.h = (_Float16)v;                       // V^T stored FP16
                    int sp = s ^ ((d & 8) ? 4 : 0);           // R13 half-swap involution
                    Vt[((long)(b * H_ + h) * DH_ + d) * S_ + sp] = cv.u;
                }
            }
}

// ---------------- 64x64 MFMA GEMM (gemm1 / Wo projection), single-buffer ----------------
// R18: 64x64 tile -> grid (16,64) = 1024 blocks = 4+ blocks/CU. LDS 16KB.
__global__ __launch_bounds__(256, 4)
void gemm_wo(const unsigned short* __restrict__ A, const unsigned short* __restrict__ Bt,
             float* __restrict__ Cout)
{
    __shared__ __align__(16) unsigned short As[64 * 64];
    __shared__ __align__(16) unsigned short Bs[64 * 64];
    const int tid  = threadIdx.x;
    const int lane = tid & 63, wid = tid >> 6;
    const int quad = lane >> 4, l15 = lane & 15;
    const int bm = blockIdx.y, bn = blockIdx.x;
    const int K = 1024;
    f32x4 acc[4] = {};
    const long Abase = (long)bm * 64 * K;
    const long Bbase = (long)bn * 64 * K;

    for (int k0 = 0; k0 < K; k0 += 64) {
        __syncthreads();
#pragma unroll
        for (int i = 0; i < 2; i++) {
            int base = i * 256 + wid * 64;
            int slot = base + lane;
            int row = slot >> 3, cp = slot & 7;
            int c = cp ^ (row & 7);
            g2l16(A + Abase + (long)row * K + k0 + c * 8, &As[base * 8]);
        }
#pragma unroll
        for (int i = 0; i < 2; i++) {
            int base = i * 256 + wid * 64;
            int slot = base + lane;
            int row = slot >> 3, cp = slot & 7;
            int c = cp ^ (row & 7);
            g2l16(Bt + Bbase + (long)row * K + k0 + c * 8, &Bs[base * 8]);
        }
        __syncthreads();
#pragma unroll
        for (int ks = 0; ks < 2; ks++) {
            bf16x8 af, bfr[4];
            {
                int ra = wid * 16 + l15;
                af = *(const bf16x8*)(As + ra * 64 + (((ks * 4 + quad) ^ (l15 & 7))) * 8);
            }
#pragma unroll
            for (int tt = 0; tt < 4; tt++) {
                int rb = tt * 16 + l15;
                bfr[tt] = *(const bf16x8*)(Bs + rb * 64 + (((ks * 4 + quad) ^ (l15 & 7))) * 8);
            }
#pragma unroll
            for (int tn = 0; tn < 4; tn++)
                acc[tn] = __builtin_amdgcn_mfma_f32_16x16x32_bf16(af, bfr[tn], acc[tn], 0, 0, 0);
        }
    }

    for (int tn = 0; tn < 4; tn++)
        for (int r = 0; r < 4; r++) {
            int gm = bm * 64 + wid * 16 + quad * 4 + r;
            int gn = bn * 64 + tn * 16 + l15;
            Cout[(long)gm * 1024 + gn] = acc[tn][r];
        }
}

// ---------------- flash attention: split-K + 4-strip K/V sharing ----------------
// R19: attn pipe model (R14): LDS ~26us / VALU ~20us / MFMA ~16us over 46.5us.
// LDS reads scale with wave-kt count (every wave reads the full 16KB K+V tile
// per kt). q-rows/wave 32 -> 64 (4 strips sharing K/V fragments) halves
// wave-kt/CU -> LDS ~13us; VALU (~20us, fixed) becomes the ceiling.
// Block = 256 q-rows, 8 waves split-K (waves 0-3 keys [0,1024), 4-7 rest),
// grid (8,32) = 256 blocks = 1/CU. VGPR ~220 -> __launch_bounds__(512,2).
// Combine: 2 passes of 128 rows through the dead K/V LDS (34KB overlay).
// R14: max-free softmax (pure exp2, fw sums to 1) => partials add directly.
// R15 V-preload, R14b l-via-MFMA, R8 register-P, R10 K=32 f16 PV packing,
// R13b V half-swap bank fix all retained.
__global__ __launch_bounds__(512, 2)
void attn_kernel(const unsigned short* __restrict__ Q, const unsigned short* __restrict__ Kb,
                 const unsigned short* __restrict__ Vt,
                 unsigned short* __restrict__ O)
{
    // [half][buf][K=0/V=1][64*64 shorts] = 64 KB
    __shared__ __align__(16) unsigned short smem[2][2][2][64 * 64];

    const int tid  = threadIdx.x;
    const int lane = tid & 63, wid = tid >> 6;    // wid in {0..7}
    const int half = wid >> 2, sw = wid & 3;      // key-half, sub-wave
    const int quad = lane >> 4, l15 = lane & 15;
    const int bh = blockIdx.y;
    const int qt = blockIdx.x;                    // 256 q-rows per block, 64 per wave

    const unsigned short* Kg = Kb + (long)bh * S_ * DH_;
    const unsigned short* Vg = Vt + (long)bh * (long)DH_ * S_;

    bf16x8 qf[4][2];
#pragma unroll
    for (int st = 0; st < 4; st++) {
        const unsigned short* Qp = Q + ((long)bh * S_ + qt * 256 + sw * 64 + st * 16 + l15) * DH_ + quad * 8;
        qf[st][0] = *(const bf16x8*)(Qp);
        qf[st][1] = *(const bf16x8*)(Qp + 32);
    }

    // stage absolute tile kt into this half's buffer: 512 chunks K + 512 V,
    // 4 sub-waves x 2 rounds each
    auto issue = [&](int buf, int kt) {
#pragma unroll
        for (int i = 0; i < 2; i++) {
            int base = i * 256 + sw * 64;
            int slot = base + lane;
            int row = slot >> 3, cp = slot & 7;
            int c = cp ^ (row & 7);
            g2l16(Kg + ((long)(kt * 64 + row) * 64 + c * 8), &smem[half][buf][0][base * 8]);
        }
#pragma unroll
        for (int i = 0; i < 2; i++) {
            int base = i * 256 + sw * 64;
            int slot = base + lane;
            int row = slot >> 3, cp = slot & 7;
            int c = cp ^ (row & 7);
            g2l16(Vg + ((long)row * S_ + kt * 64 + c * 8), &smem[half][buf][1][base * 8]);
        }
    };

    f32x4 oacc[4][4] = {};
    f32x4 lacc[4] = {};
    const f16x8 vone = {(_Float16)1.f, (_Float16)1.f, (_Float16)1.f, (_Float16)1.f,
                        (_Float16)1.f, (_Float16)1.f, (_Float16)1.f, (_Float16)1.f};

    const int kt0 = half * 16;                    // 16 tiles per half
    issue(0, kt0);
    __syncthreads();

    const int hf = (((quad & 1) ^ ((l15 >> 3) & 1))) * 4;   // R13b bank fix

    for (int t = 0; t < 16; t++) {
        const int cur = t & 1;
        if (t + 1 < 16) issue(1 - cur, kt0 + t + 1);

        const unsigned short* Kc = &smem[half][cur][0][0];
        const unsigned short* Vc = &smem[half][cur][1][0];

        // ---- S^T tiles: mfma(K_frag, Q_frag) -> [key=quad*4+r][q=l15] ----
        f32x4 sacc[4][4] = {};
#pragma unroll
        for (int kc = 0; kc < 4; kc++) {
            int row = kc * 16 + l15;
            bf16x8 k0 = *(const bf16x8*)(Kc + (row * 8 + (quad       ^ (l15 & 7))) * 8);
            bf16x8 k1 = *(const bf16x8*)(Kc + (row * 8 + ((4 + quad) ^ (l15 & 7))) * 8);
#pragma unroll
            for (int st = 0; st < 4; st++) {
                sacc[st][kc] = __builtin_amdgcn_mfma_f32_16x16x32_bf16(k0, qf[st][0], sacc[st][kc], 0, 0, 0);
                sacc[st][kc] = __builtin_amdgcn_mfma_f32_16x16x32_bf16(k1, qf[st][1], sacc[st][kc], 0, 0, 0);
            }
        }

        // ---- R15: preload ALL V fragments now; LDS drains under exp2 ----
        f16x8 vfr[2][4];
#pragma unroll
        for (int c = 0; c < 2; c++)
#pragma unroll
            for (int dt = 0; dt < 4; dt++) {
                int row = dt * 16 + l15;
                int p0 = (c * 4 +     (quad >> 1)) ^ (l15 & 7);
                int p1 = (c * 4 + 2 + (quad >> 1)) ^ (l15 & 7);
                f16x4 v0 = *(const f16x4*)(Vc + row * 64 + p0 * 8 + hf);
                f16x4 v1 = *(const f16x4*)(Vc + row * 64 + p1 * 8 + hf);
                vfr[c][dt] = __builtin_shufflevector(v0, v1, 0, 1, 2, 3, 4, 5, 6, 7);
            }

        // ---- p = 2^sacc packed into K=32 f16 PV A-fragments (R10 bijection) ----
        f16x8 pk8[4][2];
#pragma unroll
        for (int st = 0; st < 4; st++)
#pragma unroll
            for (int c = 0; c < 2; c++) {
                union { uint4 u; f16x8 v; } pku;
#pragma unroll
                for (int hh = 0; hh < 2; hh++) {
                    float p0 = __builtin_amdgcn_exp2f(sacc[st][2 * c + hh][0]);
                    float p1 = __builtin_amdgcn_exp2f(sacc[st][2 * c + hh][1]);
                    float p2 = __builtin_amdgcn_exp2f(sacc[st][2 * c + hh][2]);
                    float p3 = __builtin_amdgcn_exp2f(sacc[st][2 * c + hh][3]);
                    union { fp16x2 h2; unsigned int u; } a, b;
                    a.h2 = __builtin_amdgcn_cvt_pkrtz(p0, p1);
                    b.h2 = __builtin_amdgcn_cvt_pkrtz(p2, p3);
                    if (hh == 0) { pku.u.x = a.u; pku.u.y = b.u; }
                    else         { pku.u.z = a.u; pku.u.w = b.u; }
                }
                pk8[st][c] = pku.v;
            }

        // ---- O += P V (K=32 f16) all-register; l += P . 1 via MFMA ----
#pragma unroll
        for (int c = 0; c < 2; c++) {
#pragma unroll
            for (int st = 0; st < 4; st++)
                lacc[st] = __builtin_amdgcn_mfma_f32_16x16x32_f16(pk8[st][c], vone, lacc[st], 0, 0, 0);
#pragma unroll
            for (int dt = 0; dt < 4; dt++)
#pragma unroll
                for (int st = 0; st < 4; st++)
                    oacc[st][dt] = __builtin_amdgcn_mfma_f32_16x16x32_f16(pk8[st][c], vfr[c][dt], oacc[st][dt], 0, 0, 0);
        }

        __syncthreads();
    }
    // loop ends with a full barrier: all LDS K/V reads complete -> overlay safe

    // combine overlay over the dead K/V LDS, 2 passes of 128 q-rows:
    // pass p handles strips {2p, 2p+1}; qr' = sw*32 + (st&1)*16 + quad*4 + r
    float* ov = (float*)&smem[0][0][0][0];
    float* lv = ov + 128 * 66;
    int b = bh >> 4, h = bh & 15;

#pragma unroll
    for (int p = 0; p < 2; p++) {
        if (half == 1) {
#pragma unroll
            for (int si = 0; si < 2; si++) {
                int st = 2 * p + si;
#pragma unroll
                for (int dt = 0; dt < 4; dt++)
#pragma unroll
                    for (int r = 0; r < 4; r++) {
                        int qr = sw * 32 + si * 16 + quad * 4 + r;
                        ov[qr * 66 + dt * 16 + l15] = oacc[st][dt][r];
                    }
                if (l15 == 0) {
#pragma unroll
                    for (int r = 0; r < 4; r++)
                        lv[sw * 32 + si * 16 + quad * 4 + r] = lacc[st][r];
                }
            }
        }
        __syncthreads();
        if (half == 0) {
#pragma unroll
            for (int si = 0; si < 2; si++) {
                int st = 2 * p + si;
#pragma unroll
                for (int r = 0; r < 4; r++) {
                    int qr = sw * 32 + si * 16 + quad * 4 + r;
                    float inv = 1.0f / (lacc[st][r] + lv[qr]);
                    int srow = qt * 256 + sw * 64 + st * 16 + quad * 4 + r;
#pragma unroll
                    for (int dt = 0; dt < 4; dt++) {
                        float val = oacc[st][dt][r] + ov[qr * 66 + dt * 16 + l15];
                        O[((long)(b * S_ + srow)) * 1024 + h * DH_ + dt * 16 + l15] = f2bf(val * inv);
                    }
                }
            }
        }
        __syncthreads();
    }
}

// ---------------- launch ----------------

extern "C" void kernel_launch(void* const* d_in, const int* in_sizes, int n_in,
                              void* d_out, int out_size, void* d_ws, size_t ws_size,
                              hipStream_t stream)
{
    const float* x  = (const float*)d_in[0];
    const float* Wq = (const float*)d_in[1];
    const float* Wk = (const float*)d_in[2];
    const float* Wv = (const float*)d_in[3];
    const float* Wo = (const float*)d_in[4];
    const float* fw = (const float*)d_in[5];
    float* out = (float*)d_out;

    char* ws = (char*)d_ws;
    unsigned short* xb    = (unsigned short*)(ws);               // 8 MB   [B*S, D] bf16
    unsigned short* WqkvT = (unsigned short*)(ws + 8388608);     // 6 MB   [3072,1024] bf16
    unsigned short* WoT   = (unsigned short*)(ws + 14680064);    // 2 MB   [1024,1024] bf16
    unsigned short* Qb    = (unsigned short*)(ws + 16777216);    // 8 MB   [B,H,S,64] bf16 (pre-scaled Cq)
    unsigned short* Kb    = (unsigned short*)(ws + 25165824);    // 8 MB   [B,H,S,64] bf16 (pre-scaled fw)
    unsigned short* Vt    = (unsigned short*)(ws + 33554432);    // 8 MB   [B,H,64,S] fp16 (half-swapped)
    unsigned short* Ob    = xb;                                  // alias: xb dead after gemm1

    convert_x<<<dim3((B_ * S_ * D_) / 4 / 256), dim3(256), 0, stream>>>(x, xb, B_ * S_ * D_);
    transpose_w<<<dim3(32, 32, 4), dim3(32, 8), 0, stream>>>(
        Wq, Wk, Wv, Wo,
        WqkvT, WqkvT + 1024 * 1024, WqkvT + 2 * 1024 * 1024, WoT);
    gemm128<<<dim3(24, 32), dim3(256), 0, stream>>>(xb, WqkvT, Qb, Kb, Vt, fw);
    attn_kernel<<<dim3(S_ / 256, B_ * H_), dim3(512), 0, stream>>>(Qb, Kb, Vt, Ob);
    gemm_wo<<<dim3(16, 64), dim3(256), 0, stream>>>(Ob, WoT, out);
}